// Round 1
// baseline (500.739 us; speedup 1.0000x reference)
//
#include <hip/hip_runtime.h>
#include <stdint.h>
#include <stddef.h>

typedef __attribute__((ext_vector_type(4))) int i32x4;

#define BM 128
#define BN 128
#define BK 64

// ---------------- async global -> LDS (16B per lane) ----------------
__device__ __forceinline__ void gload_lds16(const void* g, void* l) {
    __builtin_amdgcn_global_load_lds(
        (const __attribute__((address_space(1))) void*)g,
        (__attribute__((address_space(3))) void*)l,
        16, 0, 0);
}

// ---------------- wave/block reductions ----------------
__device__ __forceinline__ float waveMaxF(float v) {
#pragma unroll
    for (int o = 32; o > 0; o >>= 1) v = fmaxf(v, __shfl_down(v, o, 64));
    return v;
}
__device__ __forceinline__ float waveMinF(float v) {
#pragma unroll
    for (int o = 32; o > 0; o >>= 1) v = fminf(v, __shfl_down(v, o, 64));
    return v;
}
__device__ __forceinline__ int waveSumI(int v) {
#pragma unroll
    for (int o = 32; o > 0; o >>= 1) v += __shfl_down(v, o, 64);
    return v;
}

// ---------------- weight quantization: row-wise symmetric int8 ----------------
// One block (256 threads) per weight row n. Two passes over the 16KB row
// (second pass hits L1). Writes Wq (int8), rscale[n] = absmax/127, rsum[n] = sum(Wq).
__global__ void __launch_bounds__(256) wquant_kernel(
    const float* __restrict__ W, int8_t* __restrict__ Wq,
    float* __restrict__ rscale, int* __restrict__ rsum, int K) {
    const int n = blockIdx.x;
    const float4* row = (const float4*)(W + (size_t)n * K);
    const int K4 = K >> 2;

    float amax = 0.f;
    for (int i = threadIdx.x; i < K4; i += 256) {
        float4 f = row[i];
        amax = fmaxf(amax, fmaxf(fmaxf(fabsf(f.x), fabsf(f.y)),
                                 fmaxf(fabsf(f.z), fabsf(f.w))));
    }
    __shared__ float smax[4];
    __shared__ int ssum[4];
    amax = waveMaxF(amax);
    const int wave = threadIdx.x >> 6;
    const int lane = threadIdx.x & 63;
    if (lane == 0) smax[wave] = amax;
    __syncthreads();
    amax = fmaxf(fmaxf(smax[0], smax[1]), fmaxf(smax[2], smax[3]));
    const float scale = (amax > 0.f) ? (amax / 127.0f) : 1.0f;

    int lsum = 0;
    char4* out = (char4*)(Wq + (size_t)n * K);
    for (int i = threadIdx.x; i < K4; i += 256) {
        float4 f = row[i];
        float q0 = fminf(fmaxf(rintf(f.x / scale), -127.f), 127.f);
        float q1 = fminf(fmaxf(rintf(f.y / scale), -127.f), 127.f);
        float q2 = fminf(fmaxf(rintf(f.z / scale), -127.f), 127.f);
        float q3 = fminf(fmaxf(rintf(f.w / scale), -127.f), 127.f);
        int i0 = (int)q0, i1 = (int)q1, i2 = (int)q2, i3 = (int)q3;
        lsum += i0 + i1 + i2 + i3;
        char4 c;
        c.x = (signed char)i0; c.y = (signed char)i1;
        c.z = (signed char)i2; c.w = (signed char)i3;
        out[i] = c;
    }
    lsum = waveSumI(lsum);
    if (lane == 0) ssum[wave] = lsum;
    __syncthreads();
    if (threadIdx.x == 0) {
        rsum[n] = ssum[0] + ssum[1] + ssum[2] + ssum[3];
        rscale[n] = scale;
    }
}

// ---------------- activation quantization: per-token asymmetric uint8 ----------------
// One block per token m. Stores (Xq - 128) as signed int8 so the GEMM can use
// signed i8 MFMA; azp[m] = 128 - zp is the rank-1 correction coefficient.
__global__ void __launch_bounds__(256) aquant_kernel(
    const float* __restrict__ X, int8_t* __restrict__ Xq,
    float* __restrict__ cscale, int* __restrict__ azp, int K) {
    const int m = blockIdx.x;
    const float4* row = (const float4*)(X + (size_t)m * K);
    const int K4 = K >> 2;

    float vmin = 3.402823466e38f, vmax = -3.402823466e38f;
    for (int i = threadIdx.x; i < K4; i += 256) {
        float4 f = row[i];
        vmin = fminf(vmin, fminf(fminf(f.x, f.y), fminf(f.z, f.w)));
        vmax = fmaxf(vmax, fmaxf(fmaxf(f.x, f.y), fmaxf(f.z, f.w)));
    }
    __shared__ float smin[4], smax[4];
    vmin = waveMinF(vmin);
    vmax = waveMaxF(vmax);
    const int wave = threadIdx.x >> 6;
    const int lane = threadIdx.x & 63;
    if (lane == 0) { smin[wave] = vmin; smax[wave] = vmax; }
    __syncthreads();
    vmin = fminf(fminf(smin[0], smin[1]), fminf(smin[2], smin[3]));
    vmax = fmaxf(fmaxf(smax[0], smax[1]), fmaxf(smax[2], smax[3]));

    const float rng = vmax - vmin;
    const float scale = (rng > 0.f) ? (rng / 255.0f) : 1.0f;
    const float zp = rintf(-vmin / scale);

    char4* out = (char4*)(Xq + (size_t)m * K);
    for (int i = threadIdx.x; i < K4; i += 256) {
        float4 f = row[i];
        float q0 = fminf(fmaxf(rintf(f.x / scale) + zp, 0.f), 255.f);
        float q1 = fminf(fmaxf(rintf(f.y / scale) + zp, 0.f), 255.f);
        float q2 = fminf(fmaxf(rintf(f.z / scale) + zp, 0.f), 255.f);
        float q3 = fminf(fmaxf(rintf(f.w / scale) + zp, 0.f), 255.f);
        char4 c;
        c.x = (signed char)((int)q0 - 128);
        c.y = (signed char)((int)q1 - 128);
        c.z = (signed char)((int)q2 - 128);
        c.w = (signed char)((int)q3 - 128);
        out[i] = c;
    }
    if (threadIdx.x == 0) {
        cscale[m] = scale;
        azp[m] = 128 - (int)zp;
    }
}

// ---------------- int8 GEMM (A: [M,K] i8, B: [N,K] i8) + dequant epilogue ----------------
// Y[m,n] = (dot_i8(A[m],B[n]) + azp[m]*rsum[n]) * cs[m]*rs[n] + bias[n]
// 128x128 tile, 4 waves, each wave does a 64x64 sub-tile = 4x4 MFMA 16x16x64 tiles.
__global__ void __launch_bounds__(256) gemm_i8_kernel(
    const int8_t* __restrict__ A, const int8_t* __restrict__ B,
    float* __restrict__ Y,
    const float* __restrict__ cs, const int* __restrict__ azp,
    const float* __restrict__ rs, const int* __restrict__ rsum,
    const float* __restrict__ bias, int M, int N, int K) {
    __shared__ int8_t As[BM * BK];  // 8 KB
    __shared__ int8_t Bs[BN * BK];  // 8 KB

    const int tid = threadIdx.x;
    const int lane = tid & 63;
    const int wave = tid >> 6;
    const int wm = wave & 1;
    const int wn = wave >> 1;
    const int quad = lane >> 4;
    const int lr = lane & 15;

    const int bm = blockIdx.x * BM;
    const int bn = blockIdx.y * BN;

    const int8_t* Ag = A + (size_t)bm * K;
    const int8_t* Bg = B + (size_t)bn * K;

    // staging: thread t loads 16B at row t/4, byte col (t&3)*16; LDS offset = tid*16
    const int srow = tid >> 2;
    const int scol = (tid & 3) << 4;

    i32x4 acc[4][4] = {};

    for (int k0 = 0; k0 < K; k0 += BK) {
        gload_lds16(Ag + (size_t)srow * K + (k0 + scol), &As[srow * BK + scol]);
        gload_lds16(Ag + (size_t)(srow + 64) * K + (k0 + scol), &As[(srow + 64) * BK + scol]);
        gload_lds16(Bg + (size_t)srow * K + (k0 + scol), &Bs[srow * BK + scol]);
        gload_lds16(Bg + (size_t)(srow + 64) * K + (k0 + scol), &Bs[(srow + 64) * BK + scol]);
        __syncthreads();  // compiler drains vmcnt before s_barrier -> LDS valid

        i32x4 af[4], bf[4];
#pragma unroll
        for (int i = 0; i < 4; ++i)
            af[i] = *(const i32x4*)&As[(wm * 64 + i * 16 + lr) * BK + quad * 16];
#pragma unroll
        for (int j = 0; j < 4; ++j)
            bf[j] = *(const i32x4*)&Bs[(wn * 64 + j * 16 + lr) * BK + quad * 16];

#pragma unroll
        for (int i = 0; i < 4; ++i)
#pragma unroll
            for (int j = 0; j < 4; ++j)
                acc[i][j] = __builtin_amdgcn_mfma_i32_16x16x64_i8(af[i], bf[j], acc[i][j], 0, 0, 0);

        __syncthreads();  // protect LDS from next iteration's staging
    }

    // epilogue: C/D layout col = lane&15 (n side), row = quad*4 + reg (m side)
#pragma unroll
    for (int i = 0; i < 4; ++i) {
        const int mb = bm + wm * 64 + i * 16 + quad * 4;
#pragma unroll
        for (int r = 0; r < 4; ++r) {
            const int m = mb + r;
            const float csm = cs[m];
            const int az = azp[m];
            float* yrow = Y + (size_t)m * N;
#pragma unroll
            for (int j = 0; j < 4; ++j) {
                const int n = bn + wn * 64 + j * 16 + lr;
                const int tot = acc[i][j][r] + az * rsum[n];
                yrow[n] = fmaf((float)tot, csm * rs[n], bias[n]);
            }
        }
    }
}

// ---------------- launch ----------------
extern "C" void kernel_launch(void* const* d_in, const int* in_sizes, int n_in,
                              void* d_out, int out_size, void* d_ws, size_t ws_size,
                              hipStream_t stream) {
    const float* x = (const float*)d_in[0];
    const float* w = (const float*)d_in[1];
    const float* bias = (const float*)d_in[2];
    float* y = (float*)d_out;

    const int N = in_sizes[2];            // 4096
    const int K = in_sizes[1] / N;        // 4096
    const int M = in_sizes[0] / K;        // 8192

    uint8_t* ws = (uint8_t*)d_ws;
    int8_t* Wq = (int8_t*)ws;                                  // N*K   int8
    int8_t* Xq = (int8_t*)(ws + (size_t)N * K);                // M*K   int8
    uint8_t* p = ws + (size_t)N * K + (size_t)M * K;
    p = (uint8_t*)(((uintptr_t)p + 255) & ~(uintptr_t)255);
    float* rscale = (float*)p;  p += (size_t)N * sizeof(float);
    int*   rsum   = (int*)p;    p += (size_t)N * sizeof(int);
    float* cscale = (float*)p;  p += (size_t)M * sizeof(float);
    int*   azp    = (int*)p;    p += (size_t)M * sizeof(int);

    wquant_kernel<<<N, 256, 0, stream>>>(w, Wq, rscale, rsum, K);
    aquant_kernel<<<M, 256, 0, stream>>>(x, Xq, cscale, azp, K);

    dim3 grid(M / BM, N / BN);
    gemm_i8_kernel<<<grid, 256, 0, stream>>>(Xq, Wq, y, cscale, azp,
                                             rscale, rsum, bias, M, N, K);
}